// Round 18
// baseline (212.526 us; speedup 1.0000x reference)
//
#include <hip/hip_runtime.h>
#include <stdint.h>

// Problem constants
#define B_SZ 4
#define L_SEQ 8192
#define D_CH 768
#define K_F 24
#define NFFT2 8192       // FFT size after parity split (2*4096)
#define LDS_BYTES 69632  // 8704 cplx (padded: phi(i) = i + (i>>4))
#define GEMM_LDS 49152   // As [128][64] fp32 (32KB) + Bs [128][64] bf16 (16KB) -> 3 blocks/CU

typedef __attribute__((ext_vector_type(4))) float f32x4;
typedef __attribute__((ext_vector_type(8))) __bf16 bf16x8;
typedef __attribute__((ext_vector_type(2))) float v2f;  // complex: {re, im} -> v_pk_* ops

// ---------- bf16 helpers ----------
__device__ __forceinline__ uint32_t f2bf1(float f) {
  uint32_t u = __float_as_uint(f);
  return (u + 0x7fffu + ((u >> 16) & 1u)) >> 16;
}
__device__ __forceinline__ v2f unpackbf2(uint32_t v) {
  return v2f{__uint_as_float(v << 16), __uint_as_float(v & 0xffff0000u)};
}
__device__ __forceinline__ uint32_t pkbf(float lo, float hi) {  // hw RNE pack
  uint32_t r;
  asm("v_cvt_pk_bf16_f32 %0, %1, %2" : "=v"(r) : "v"(lo), "v"(hi));
  return r;
}

// ---------- packed complex arithmetic (maps to v_pk_add/mul/fma_f32) ----------
__device__ __forceinline__ v2f rotm(v2f v) { return v2f{v.y, -v.x}; }   // v * (-i)
__device__ __forceinline__ v2f rotp(v2f v) { return v2f{-v.y, v.x}; }   // v * (+i)
__device__ __forceinline__ v2f cmulf(v2f a, v2f b) {
  return a.x * b + a.y * rotp(b);  // pk_mul + pk_fma (neg/op_sel fold)
}

// squaring-tree twiddle fan-out: tw[i] = w^{i+1} from tw[0] = w (depth 3)
__device__ __forceinline__ void twfill(v2f* tw) {
  tw[1] = cmulf(tw[0], tw[0]);
  tw[3] = cmulf(tw[1], tw[1]);
  tw[2] = cmulf(tw[0], tw[1]);
  tw[4] = cmulf(tw[3], tw[0]);
  tw[5] = cmulf(tw[3], tw[1]);
  tw[6] = cmulf(tw[3], tw[2]);
}

// MiT[n][e] = Mi[e][n], bf16
__global__ __launch_bounds__(256) void k_mit(const float* __restrict__ Mi,
                                             uint16_t* __restrict__ MiT) {
  int i = blockIdx.x * 256 + threadIdx.x;  // = n*768 + e
  int n = i / 768, e = i - n * 768;
  MiT[i] = (uint16_t)f2bf1(Mi[e * 768 + n]);
}

// ---------- radix-8 DFT building block (vector-form: adds are v_pk_add_f32) ----------
// S=-1: forward (W8 = e^{-2pi i/8}); S=+1: inverse (unnormalized, W8^{-1})
template <int S>
__device__ __forceinline__ void dft8(v2f* x) {
  const float C = 0.70710678118654752f;
  v2f t0 = x[0] + x[4], t1 = x[0] - x[4];
  v2f t2 = x[2] + x[6], t3 = x[2] - x[6];
  v2f t4 = x[1] + x[5], t5 = x[1] - x[5];
  v2f t6 = x[3] + x[7], t7 = x[3] - x[7];
  v2f t3r = (S < 0) ? rotm(t3) : rotp(t3);
  v2f t7r = (S < 0) ? rotm(t7) : rotp(t7);
  v2f e0 = t0 + t2, e2 = t0 - t2;
  v2f e1 = t1 + t3r, e3 = t1 - t3r;
  v2f o0 = t4 + t6, o2 = t4 - t6;
  v2f o1 = t5 + t7r, o3 = t5 - t7r;
  v2f o1r = (S < 0) ? C * (o1 + rotm(o1)) : C * (o1 + rotp(o1));
  v2f o2r = (S < 0) ? rotm(o2) : rotp(o2);
  v2f o3r = (S < 0) ? C * (rotm(o3) - o3) : C * (rotp(o3) - o3);
  x[0] = e0 + o0;
  x[4] = e0 - o0;
  x[1] = e1 + o1r;
  x[5] = e1 - o1r;
  x[2] = e2 + o2r;
  x[6] = e2 - o2r;
  x[3] = e3 + o3r;
  x[7] = e3 - o3r;
}

// Generic radix-8 LDS pass on padded layout. Twiddle set hoisted out of the jj
// loop when h <= NT (pos = tid & (h-1) is jj-invariant).
template <int LH, int S, int NT>
__device__ __forceinline__ void pass_r8(v2f* a, int tid) {
  constexpr int h = 1 << LH;
  constexpr int st = h + (h >> 4);
  const float ang = (S < 0 ? -6.2831853071795864769f : 6.2831853071795864769f) / (float)(h * 8);
  v2f tw[7];
  if constexpr (h <= NT) {
    float sn, cs;
    __sincosf(ang * (float)(tid & (h - 1)), &sn, &cs);
    tw[0] = v2f{cs, sn};
    twfill(tw);
  }
  __syncthreads();
#pragma unroll
  for (int jj = 0; jj < 1024 / NT; ++jj) {
    int j = jj * NT + tid;
    int pos = j & (h - 1);
    int base = ((j >> LH) << (LH + 3)) + pos;
    v2f* p = a + (base + (base >> 4));
    if constexpr (h > NT) {
      float sn, cs;
      __sincosf(ang * (float)pos, &sn, &cs);
      tw[0] = v2f{cs, sn};
      twfill(tw);
    }
    v2f x[8];
#pragma unroll
    for (int q = 0; q < 8; ++q) x[q] = p[q * st];
    if constexpr (S < 0) {
      dft8<-1>(x);
#pragma unroll
      for (int q = 1; q < 8; ++q) x[q] = cmulf(x[q], tw[q - 1]);
    } else {
#pragma unroll
      for (int q = 1; q < 8; ++q) x[q] = cmulf(x[q], tw[q - 1]);
      dft8<1>(x);
    }
#pragma unroll
    for (int q = 0; q < 8; ++q) p[q * st] = x[q];
  }
}

// Fused first forward pass (h=1024): read packed bf16 row from global, upper half zero.
// jj=1 base twiddle = jj=0's rotated by e^{-i*pi/8} (one sincos total).
__device__ __forceinline__ void p1_fused(v2f* a, const uint32_t* __restrict__ row32, int tid) {
  const float CP = 0.92387953251128675613f, SP = 0.38268343236508977173f;
  float sn, cs;
  __sincosf(-6.2831853071795864769f / 8192.0f * (float)tid, &sn, &cs);
  v2f w1{cs, sn};
#pragma unroll
  for (int jj = 0; jj < 2; ++jj) {
    int j = jj * 512 + tid;
    v2f x[8];
#pragma unroll
    for (int q = 0; q < 4; ++q) x[q] = unpackbf2(row32[j + q * 1024]);
    x[4] = x[5] = x[6] = x[7] = v2f{0.f, 0.f};  // const-folded through dft8
    dft8<-1>(x);
    v2f tw[7];
    tw[0] = w1;
    twfill(tw);
#pragma unroll
    for (int q = 1; q < 8; ++q) x[q] = cmulf(x[q], tw[q - 1]);
    v2f* p = a + (j + (j >> 4));
#pragma unroll
    for (int q = 0; q < 8; ++q) p[q * 1088] = x[q];
    w1 = cmulf(w1, v2f{CP, -SP});  // advance pos by 512
  }
}

// In-register fused middle: fwd radix-8(h=2) + fwd r2 + xW2 + inv r2 + inv radix-8(h=2).
// Each thread owns EXACTLY ONE group of 16 consecutive points (512 thr x 16 = 8192);
// padded layout: pad(16m+i) = 17m+i. h=2 twiddles are compile-time W16^q.
__device__ __forceinline__ void mid16(v2f* a, const uint32_t* __restrict__ wrow, int tid) {
  const float C1 = 0.92387953251128675613f, S1 = 0.38268343236508977173f;
  const float C2 = 0.70710678118654752440f;
  __syncthreads();
  int m = tid;
  v2f* p = a + 17 * m;  // 16 consecutive padded entries
  v2f e[8], o[8];
#pragma unroll
  for (int q = 0; q < 8; ++q) {
    e[q] = p[2 * q];
    o[q] = p[2 * q + 1];
  }
  // forward radix-8, h=2: even butterfly (pos=0, unity), odd (pos=1, W16^q)
  dft8<-1>(e);
  dft8<-1>(o);
  o[1] = cmulf(o[1], v2f{C1, -S1});
  o[2] = cmulf(o[2], v2f{C2, -C2});
  o[3] = cmulf(o[3], v2f{S1, -C1});
  o[4] = rotm(o[4]);
  o[5] = cmulf(o[5], v2f{-S1, -C1});
  o[6] = cmulf(o[6], v2f{-C2, -C2});
  o[7] = cmulf(o[7], v2f{-C1, -S1});
  // fwd r2 (pairs 2q,2q+1) + xW2 + inv r2
  const uint4* wp = (const uint4*)(wrow + 16 * m);
  uint4 w0 = wp[0], w1 = wp[1], w2 = wp[2], w3 = wp[3];
  uint32_t wv[16] = {w0.x, w0.y, w0.z, w0.w, w1.x, w1.y, w1.z, w1.w,
                     w2.x, w2.y, w2.z, w2.w, w3.x, w3.y, w3.z, w3.w};
#pragma unroll
  for (int q = 0; q < 8; ++q) {
    v2f s = e[q] + o[q];
    v2f d = e[q] - o[q];
    s = cmulf(s, unpackbf2(wv[2 * q]));
    d = cmulf(d, unpackbf2(wv[2 * q + 1]));
    e[q] = s + d;
    o[q] = s - d;
  }
  // inverse radix-8, h=2: conj twiddle odd, then idft8
  o[1] = cmulf(o[1], v2f{C1, S1});
  o[2] = cmulf(o[2], v2f{C2, C2});
  o[3] = cmulf(o[3], v2f{S1, C1});
  o[4] = rotp(o[4]);
  o[5] = cmulf(o[5], v2f{-S1, C1});
  o[6] = cmulf(o[6], v2f{-C2, C2});
  o[7] = cmulf(o[7], v2f{-C1, S1});
  dft8<1>(e);
  dft8<1>(o);
#pragma unroll
  for (int q = 0; q < 8; ++q) {
    p[2 * q] = e[q];
    p[2 * q + 1] = o[q];
  }
}

// Fused last inverse pass (h=1024): pack bf16 + store; keep only first 4096 outputs.
__device__ __forceinline__ void last_fused(v2f* a, uint32_t* __restrict__ out32, int tid) {
  const float CP = 0.92387953251128675613f, SP = 0.38268343236508977173f;
  float sn, cs;
  __sincosf(6.2831853071795864769f / 8192.0f * (float)tid, &sn, &cs);
  v2f w1{cs, sn};
  __syncthreads();
#pragma unroll
  for (int jj = 0; jj < 2; ++jj) {
    int j = jj * 512 + tid;
    v2f* p = a + (j + (j >> 4));
    v2f x[8];
#pragma unroll
    for (int q = 0; q < 8; ++q) x[q] = p[q * 1088];
    v2f tw[7];
    tw[0] = w1;
    twfill(tw);
#pragma unroll
    for (int q = 1; q < 8; ++q) x[q] = cmulf(x[q], tw[q - 1]);
    dft8<1>(x);  // x[4..7] unused below -> their final adds are DCE'd
#pragma unroll
    for (int q = 0; q < 4; ++q) out32[j + q * 1024] = pkbf(x[q].x, x[q].y);
    w1 = cmulf(w1, v2f{CP, SP});  // advance pos by 512
  }
}

// Phi2[k][f] = fwd-FFT( pad( (2/8192)*phi[2r,k], r<4096 ) ), scrambled order (matches k_conv)
__global__ __launch_bounds__(512) void k_phi(const float* __restrict__ phi,
                                             v2f* __restrict__ Phi2) {
  extern __shared__ v2f buf[];
  int k = blockIdx.x, tid = threadIdx.x;
  const float scale = 2.0f / 8192.0f;
  for (int r = tid; r < 4096; r += 512) {
    buf[r + (r >> 4)] = v2f{phi[(2 * r) * K_F + k] * scale, 0.0f};
    int r2i = r + 4096;
    buf[r2i + (r2i >> 4)] = v2f{0.0f, 0.0f};
  }
  pass_r8<10, -1, 512>(buf, tid);
  pass_r8<7, -1, 512>(buf, tid);
  pass_r8<4, -1, 512>(buf, tid);
  pass_r8<1, -1, 512>(buf, tid);
  __syncthreads();
  for (int j = tid; j < 4096; j += 512) {  // forward radix-2 (h=1)
    v2f* p = buf + (2 * j + ((2 * j) >> 4));
    v2f u = p[0], v = p[1];
    p[0] = u + v;
    p[1] = u - v;
  }
  __syncthreads();
  for (int f = tid; f < NFFT2; f += 512) Phi2[k * NFFT2 + f] = buf[f + (f >> 4)];
}

// W2[d][f] = sum_k Mf[k][d] * Phi2[k][f]  (packed bf16 re|im)
__global__ __launch_bounds__(256) void k_w2(const v2f* __restrict__ Phi2,
                                            const float* __restrict__ Mf,
                                            uint32_t* __restrict__ W2) {
  __shared__ v2f p[K_F][256];
  __shared__ float mf[K_F][32];
  int tid = threadIdx.x;
  int fc = blockIdx.x & 31, dc = blockIdx.x >> 5;
  int f0 = fc * 256, d0 = dc * 32;
  for (int i = tid; i < K_F * 256; i += 256) {
    int k = i >> 8, fl = i & 255;
    p[k][fl] = Phi2[k * NFFT2 + f0 + fl];
  }
  for (int i = tid; i < K_F * 32; i += 256) {
    int k = i >> 5, dl = i & 31;
    mf[k][dl] = Mf[k * D_CH + d0 + dl];
  }
  __syncthreads();
  for (int dl = 0; dl < 32; ++dl) {
    v2f acc = v2f{0.f, 0.f};
#pragma unroll
    for (int k = 0; k < K_F; ++k) acc += mf[k][dl] * p[k][tid];
    W2[(size_t)(d0 + dl) * NFFT2 + f0 + tid] = pkbf(acc.x, acc.y);
  }
}

// ---------- bf16 MFMA GEMM: m97 single-buffer structure, ALL-DMA staging (R12) ----------
// A staged as fp32 via global_load_lds (no VGPRs -> compiler cannot sink the prefetch);
// converted to bf16 with v_cvt_pk at fragment-read time. 48 KB LDS -> 3 blocks/CU.
__device__ __forceinline__ void gload_lds16(const void* g, void* l) {
  __builtin_amdgcn_global_load_lds(
      (const __attribute__((address_space(1))) void*)g,
      (__attribute__((address_space(3))) void*)l, 16, 0, 0);
}

__global__ __launch_bounds__(256) void k_gemm(const float* __restrict__ X,
                                              const uint16_t* __restrict__ MiT,
                                              uint16_t* __restrict__ Cp) {
  extern __shared__ char lds[];
  char* const As0 = lds;            // [128 rows][64 k] fp32, 16B-slot XOR swizzle (32 KB)
  char* const Bs0 = lds + 32768;    // [128 rows][64 k] bf16, XOR swizzle (16 KB)
  int tid = threadIdx.x;
  int lane = tid & 63, wid = tid >> 6;
  // bijective XCD swizzle: 1536 wg = 8 XCD x 192; 6 bn-siblings of a bm share one XCD L2
  int pb = blockIdx.x;
  int v = (pb & 7) * 192 + (pb >> 3);
  int bm = v / 6, bn = v % 6;
  int m0 = bm * 128, n0 = bn * 128;
  int wr = wid >> 1, wc = wid & 1;  // 2 x 2 waves, per-wave 64x64 output
  int lm = lane & 15, lg = lane >> 4;
  f32x4 acc[4][4] = {};

#define STAGE_A(k0)                                                     \
  _Pragma("unroll") for (int it = 0; it < 8; ++it) {                    \
    int s = it * 256 + tid;                                             \
    int row = s >> 4, s16 = s & 15;                                     \
    gload_lds16(X + (size_t)(m0 + row) * 768 + (k0) + ((s16 ^ (row & 7)) << 2), \
                As0 + (it * 256 + wid * 64) * 16);                      \
  }
#define STAGE_B(k0)                                                     \
  _Pragma("unroll") for (int it = 0; it < 4; ++it) {                    \
    int s = it * 256 + tid;                                             \
    int row = s >> 3;                                                   \
    int cb = ((s & 7) << 4) ^ ((row & 7) << 4);                         \
    gload_lds16(MiT + (size_t)(n0 + row) * 768 + (k0) + (cb >> 1),      \
                Bs0 + (it * 256 + wid * 64) * 16);                      \
  }

  for (int kt = 0; kt < 12; ++kt) {
    __syncthreads();  // previous tile's reads complete before overwrite
    STAGE_A(kt * 64);
    STAGE_B(kt * 64);
    asm volatile("s_waitcnt vmcnt(0)" ::: "memory");
    __syncthreads();
#pragma unroll
    for (int ks = 0; ks < 2; ++ks) {
      bf16x8 a[4], b[4];
#pragma unroll
      for (int mi = 0; mi < 4; ++mi) {
        int row = wr * 64 + mi * 16 + lm;
        const char* rb = As0 + row * 256;
        int s0 = ks * 8 + lg * 2;
        float4 flo = *(const float4*)(rb + ((s0 ^ (row & 7)) << 4));
        float4 fhi = *(const float4*)(rb + (((s0 + 1) ^ (row & 7)) << 4));
        uint4 u;
        u.x = pkbf(flo.x, flo.y);
        u.y = pkbf(flo.z, flo.w);
        u.z = pkbf(fhi.x, fhi.y);
        u.w = pkbf(fhi.z, fhi.w);
        a[mi] = *(const bf16x8*)&u;
      }
      int kbyte = (ks * 32 + lg * 8) * 2;
#pragma unroll
      for (int ni = 0; ni < 4; ++ni) {
        int row = wc * 64 + ni * 16 + lm;
        b[ni] = *(const bf16x8*)(Bs0 + row * 128 + (kbyte ^ ((row & 7) << 4)));
      }
#pragma unroll
      for (int mi = 0; mi < 4; ++mi)
#pragma unroll
        for (int ni = 0; ni < 4; ++ni)
          acc[mi][ni] = __builtin_amdgcn_mfma_f32_16x16x32_bf16(a[mi], b[ni], acc[mi][ni], 0, 0, 0);
    }
  }
#undef STAGE_A
#undef STAGE_B

  // epilogue: write transposed (B,D,L) bf16, 4 t-contig per lane
#pragma unroll
  for (int mi = 0; mi < 4; ++mi) {
#pragma unroll
    for (int ni = 0; ni < 4; ++ni) {
      int mg = m0 + wr * 64 + mi * 16 + lg * 4;
      int dd = n0 + wc * 64 + ni * 16 + lm;
      int bb = mg >> 13, t = mg & 8191;
      f32x4 vv = acc[mi][ni];
      uint2 o;
      o.x = pkbf(vv[0], vv[1]);
      o.y = pkbf(vv[2], vv[3]);
      *(uint2*)(Cp + ((size_t)bb * 768 + dd) * 8192 + t) = o;
    }
  }
}

// ---------- per-(b,d) FFT conv: 7-pass pipeline with in-register fused middle ----------
__global__ __launch_bounds__(512, 4) void k_conv(const uint16_t* __restrict__ xprojT,
                                                 const uint32_t* __restrict__ W2,
                                                 uint16_t* __restrict__ convo) {
  extern __shared__ v2f buf[];
  int tid = threadIdx.x;
  int bd = blockIdx.x;  // b*768 + d
  int d = bd % 768;
  const uint32_t* row32 = (const uint32_t*)(xprojT + (size_t)bd * 8192);
  p1_fused(buf, row32, tid);
  pass_r8<7, -1, 512>(buf, tid);
  pass_r8<4, -1, 512>(buf, tid);
  mid16(buf, W2 + (size_t)d * NFFT2, tid);
  pass_r8<4, 1, 512>(buf, tid);
  pass_r8<7, 1, 512>(buf, tid);
  last_fused(buf, (uint32_t*)(convo + (size_t)bd * 8192), tid);
}

// ---------- transpose (B,D,L) bf16 -> (B,L,D) fp32 ----------
__global__ __launch_bounds__(256) void k_tr(const uint16_t* __restrict__ convo,
                                            float* __restrict__ out) {
  __shared__ uint16_t tile[64][72];
  int tid = threadIdx.x;
  int bx = blockIdx.x;
  int b = bx / 1536;
  int r = bx - b * 1536;
  int d0 = (r >> 7) << 6;
  int t0 = (r & 127) << 6;
  {
    int rr = tid >> 3;
    int c8 = (tid & 7) << 3;
#pragma unroll
    for (int p = 0; p < 2; ++p) {
      int row = p * 32 + rr;
      uint4 v = *(const uint4*)(convo + ((size_t)(b * 768 + d0 + row)) * 8192 + t0 + c8);
      *(uint4*)&tile[row][c8] = v;
    }
  }
  __syncthreads();
  {
    int c4 = (tid & 15) << 2;
    int tg = tid >> 4;
#pragma unroll
    for (int p = 0; p < 4; ++p) {
      int tt = p * 16 + tg;
      float4 o;
      o.x = __uint_as_float((uint32_t)tile[c4 + 0][tt] << 16);
      o.y = __uint_as_float((uint32_t)tile[c4 + 1][tt] << 16);
      o.z = __uint_as_float((uint32_t)tile[c4 + 2][tt] << 16);
      o.w = __uint_as_float((uint32_t)tile[c4 + 3][tt] << 16);
      *(float4*)(out + ((size_t)b * 8192 + t0 + tt) * 768 + d0 + c4) = o;
    }
  }
}

extern "C" void kernel_launch(void* const* d_in, const int* in_sizes, int n_in,
                              void* d_out, int out_size, void* d_ws, size_t ws_size,
                              hipStream_t stream) {
  const float* x   = (const float*)d_in[0];
  const float* phi = (const float*)d_in[1];
  const float* Mi  = (const float*)d_in[2];
  const float* Mf  = (const float*)d_in[3];
  float* out = (float*)d_out;

  // d_out doubles as staging: [48MB,96MB) x_projT bf16 (B,D,L); [0,48MB) unused until k_tr
  uint16_t* xprojT = (uint16_t*)d_out + 25165824;

  char* ws = (char*)d_ws;
  uint16_t* convo = (uint16_t*)ws;               // 50,331,648 B  (B,D,L) bf16 conv result
  uint32_t* W2    = (uint32_t*)(ws + 50331648);  // 25,165,824 B  [768][8192] bf16 re|im
  v2f*      Phi2  = (v2f*)(ws + 75497472);       //  1,572,864 B  [24][8192] fp32 complex
  uint16_t* MiT   = (uint16_t*)(ws + 77070336);  //  1,179,648 B  [768][768] bf16

  k_mit<<<2304, 256, 0, stream>>>(Mi, MiT);
  k_phi<<<24, 512, LDS_BYTES, stream>>>(phi, Phi2);
  k_w2<<<768, 256, 0, stream>>>(Phi2, Mf, W2);
  k_gemm<<<1536, 256, GEMM_LDS, stream>>>(x, MiT, xprojT);
  k_conv<<<3072, 512, LDS_BYTES, stream>>>(xprojT, W2, convo);
  k_tr<<<6144, 256, 0, stream>>>(convo, out);
}

// Round 19
// 201.715 us; speedup vs baseline: 1.0536x; 1.0536x over previous
//
#include <hip/hip_runtime.h>
#include <stdint.h>

// Problem constants
#define B_SZ 4
#define L_SEQ 8192
#define D_CH 768
#define K_F 24
#define NFFT2 8192       // FFT size after parity split (2*4096)
#define LDS_BYTES 69632  // 8704 cplx (padded: phi(i) = i + (i>>4))
#define GEMM_LDS 49152   // As [128][64] fp32 (32KB) + Bs [128][64] bf16 (16KB) -> 3 blocks/CU

typedef __attribute__((ext_vector_type(4))) float f32x4;
typedef __attribute__((ext_vector_type(8))) __bf16 bf16x8;
typedef __attribute__((ext_vector_type(2))) float v2f;  // complex: {re, im} -> v_pk_* ops

// ---------- bf16 helpers (RNE) ----------
__device__ __forceinline__ uint32_t f2bf1(float f) {
  uint32_t u = __float_as_uint(f);
  return (u + 0x7fffu + ((u >> 16) & 1u)) >> 16;
}
__device__ __forceinline__ uint32_t packbf2(float lo, float hi) {
  return f2bf1(lo) | (f2bf1(hi) << 16);
}
__device__ __forceinline__ v2f unpackbf2(uint32_t v) {
  return v2f{__uint_as_float(v << 16), __uint_as_float(v & 0xffff0000u)};
}
__device__ __forceinline__ uint32_t pkbf(float lo, float hi) {
  uint32_t r;
  asm("v_cvt_pk_bf16_f32 %0, %1, %2" : "=v"(r) : "v"(lo), "v"(hi));
  return r;
}

// ---------- packed complex arithmetic (maps to v_pk_add/mul/fma_f32) ----------
__device__ __forceinline__ v2f rotm(v2f v) { return v2f{v.y, -v.x}; }   // v * (-i)
__device__ __forceinline__ v2f rotp(v2f v) { return v2f{-v.y, v.x}; }   // v * (+i)
__device__ __forceinline__ v2f cmulf(v2f a, v2f b) {
  return a.x * b + a.y * rotp(b);  // pk_mul + pk_fma (neg/op_sel fold)
}

// squaring-tree twiddle fan-out: tw[i] = w^{i+1} from tw[0] = w (depth 3)
__device__ __forceinline__ void twfill(v2f* tw) {
  tw[1] = cmulf(tw[0], tw[0]);
  tw[3] = cmulf(tw[1], tw[1]);
  tw[2] = cmulf(tw[0], tw[1]);
  tw[4] = cmulf(tw[3], tw[0]);
  tw[5] = cmulf(tw[3], tw[1]);
  tw[6] = cmulf(tw[3], tw[2]);
}

// MiT[n][e] = Mi[e][n], bf16
__global__ __launch_bounds__(256) void k_mit(const float* __restrict__ Mi,
                                             uint16_t* __restrict__ MiT) {
  int i = blockIdx.x * 256 + threadIdx.x;  // = n*768 + e
  int n = i / 768, e = i - n * 768;
  MiT[i] = (uint16_t)f2bf1(Mi[e * 768 + n]);
}

// ---------- radix-8 DFT building block (vector-form: adds are v_pk_add_f32) ----------
// S=-1: forward (W8 = e^{-2pi i/8}); S=+1: inverse (unnormalized, W8^{-1})
template <int S>
__device__ __forceinline__ void dft8(v2f* x) {
  const float C = 0.70710678118654752f;
  v2f t0 = x[0] + x[4], t1 = x[0] - x[4];
  v2f t2 = x[2] + x[6], t3 = x[2] - x[6];
  v2f t4 = x[1] + x[5], t5 = x[1] - x[5];
  v2f t6 = x[3] + x[7], t7 = x[3] - x[7];
  v2f t3r = (S < 0) ? rotm(t3) : rotp(t3);
  v2f t7r = (S < 0) ? rotm(t7) : rotp(t7);
  v2f e0 = t0 + t2, e2 = t0 - t2;
  v2f e1 = t1 + t3r, e3 = t1 - t3r;
  v2f o0 = t4 + t6, o2 = t4 - t6;
  v2f o1 = t5 + t7r, o3 = t5 - t7r;
  v2f o1r = (S < 0) ? C * (o1 + rotm(o1)) : C * (o1 + rotp(o1));
  v2f o2r = (S < 0) ? rotm(o2) : rotp(o2);
  v2f o3r = (S < 0) ? C * (rotm(o3) - o3) : C * (rotp(o3) - o3);
  x[0] = e0 + o0;
  x[4] = e0 - o0;
  x[1] = e1 + o1r;
  x[5] = e1 - o1r;
  x[2] = e2 + o2r;
  x[6] = e2 - o2r;
  x[3] = e3 + o3r;
  x[7] = e3 - o3r;
}

// Generic radix-8 LDS pass on padded layout. Twiddle set hoisted out of the jj
// loop when h <= NT (pos = tid & (h-1) is jj-invariant).
template <int LH, int S, int NT>
__device__ __forceinline__ void pass_r8(v2f* a, int tid) {
  constexpr int h = 1 << LH;
  constexpr int st = h + (h >> 4);
  const float ang = (S < 0 ? -6.2831853071795864769f : 6.2831853071795864769f) / (float)(h * 8);
  v2f tw[7];
  if constexpr (h <= NT) {
    float sn, cs;
    __sincosf(ang * (float)(tid & (h - 1)), &sn, &cs);
    tw[0] = v2f{cs, sn};
    twfill(tw);
  }
  __syncthreads();
#pragma unroll
  for (int jj = 0; jj < 1024 / NT; ++jj) {
    int j = jj * NT + tid;
    int pos = j & (h - 1);
    int base = ((j >> LH) << (LH + 3)) + pos;
    v2f* p = a + (base + (base >> 4));
    if constexpr (h > NT) {
      float sn, cs;
      __sincosf(ang * (float)pos, &sn, &cs);
      tw[0] = v2f{cs, sn};
      twfill(tw);
    }
    v2f x[8];
#pragma unroll
    for (int q = 0; q < 8; ++q) x[q] = p[q * st];
    if constexpr (S < 0) {
      dft8<-1>(x);
#pragma unroll
      for (int q = 1; q < 8; ++q) x[q] = cmulf(x[q], tw[q - 1]);
    } else {
#pragma unroll
      for (int q = 1; q < 8; ++q) x[q] = cmulf(x[q], tw[q - 1]);
      dft8<1>(x);
    }
#pragma unroll
    for (int q = 0; q < 8; ++q) p[q * st] = x[q];
  }
}

// Fused first forward pass (h=1024): read packed bf16 row from global, upper half zero.
// jj=1 base twiddle = jj=0's rotated by e^{-i*pi/8} (one sincos total).
__device__ __forceinline__ void p1_fused(v2f* a, const uint32_t* __restrict__ row32, int tid) {
  const float CP = 0.92387953251128675613f, SP = 0.38268343236508977173f;
  float sn, cs;
  __sincosf(-6.2831853071795864769f / 8192.0f * (float)tid, &sn, &cs);
  v2f w1{cs, sn};
#pragma unroll
  for (int jj = 0; jj < 2; ++jj) {
    int j = jj * 512 + tid;
    v2f x[8];
#pragma unroll
    for (int q = 0; q < 4; ++q) x[q] = unpackbf2(row32[j + q * 1024]);
    x[4] = x[5] = x[6] = x[7] = v2f{0.f, 0.f};  // const-folded through dft8
    dft8<-1>(x);
    v2f tw[7];
    tw[0] = w1;
    twfill(tw);
#pragma unroll
    for (int q = 1; q < 8; ++q) x[q] = cmulf(x[q], tw[q - 1]);
    v2f* p = a + (j + (j >> 4));
#pragma unroll
    for (int q = 0; q < 8; ++q) p[q * 1088] = x[q];
    w1 = cmulf(w1, v2f{CP, -SP});  // advance pos by 512
  }
}

// In-register fused middle: fwd radix-8(h=2) + fwd r2 + xW2 + inv r2 + inv radix-8(h=2).
// Each thread owns EXACTLY ONE group of 16 consecutive points (512 thr x 16 = 8192);
// padded layout: pad(16m+i) = 17m+i. h=2 twiddles are compile-time W16^q.
__device__ __forceinline__ void mid16(v2f* a, const uint32_t* __restrict__ wrow, int tid) {
  const float C1 = 0.92387953251128675613f, S1 = 0.38268343236508977173f;
  const float C2 = 0.70710678118654752440f;
  __syncthreads();
  int m = tid;
  v2f* p = a + 17 * m;  // 16 consecutive padded entries
  v2f e[8], o[8];
#pragma unroll
  for (int q = 0; q < 8; ++q) {
    e[q] = p[2 * q];
    o[q] = p[2 * q + 1];
  }
  // forward radix-8, h=2: even butterfly (pos=0, unity), odd (pos=1, W16^q)
  dft8<-1>(e);
  dft8<-1>(o);
  o[1] = cmulf(o[1], v2f{C1, -S1});
  o[2] = cmulf(o[2], v2f{C2, -C2});
  o[3] = cmulf(o[3], v2f{S1, -C1});
  o[4] = rotm(o[4]);
  o[5] = cmulf(o[5], v2f{-S1, -C1});
  o[6] = cmulf(o[6], v2f{-C2, -C2});
  o[7] = cmulf(o[7], v2f{-C1, -S1});
  // fwd r2 (pairs 2q,2q+1) + xW2 + inv r2
  const uint4* wp = (const uint4*)(wrow + 16 * m);
  uint4 w0 = wp[0], w1 = wp[1], w2 = wp[2], w3 = wp[3];
  uint32_t wv[16] = {w0.x, w0.y, w0.z, w0.w, w1.x, w1.y, w1.z, w1.w,
                     w2.x, w2.y, w2.z, w2.w, w3.x, w3.y, w3.z, w3.w};
#pragma unroll
  for (int q = 0; q < 8; ++q) {
    v2f s = e[q] + o[q];
    v2f d = e[q] - o[q];
    s = cmulf(s, unpackbf2(wv[2 * q]));
    d = cmulf(d, unpackbf2(wv[2 * q + 1]));
    e[q] = s + d;
    o[q] = s - d;
  }
  // inverse radix-8, h=2: conj twiddle odd, then idft8
  o[1] = cmulf(o[1], v2f{C1, S1});
  o[2] = cmulf(o[2], v2f{C2, C2});
  o[3] = cmulf(o[3], v2f{S1, C1});
  o[4] = rotp(o[4]);
  o[5] = cmulf(o[5], v2f{-S1, C1});
  o[6] = cmulf(o[6], v2f{-C2, C2});
  o[7] = cmulf(o[7], v2f{-C1, S1});
  dft8<1>(e);
  dft8<1>(o);
#pragma unroll
  for (int q = 0; q < 8; ++q) {
    p[2 * q] = e[q];
    p[2 * q + 1] = o[q];
  }
}

// Fused last inverse pass (h=1024): pack bf16 + store; keep only first 4096 outputs.
__device__ __forceinline__ void last_fused(v2f* a, uint32_t* __restrict__ out32, int tid) {
  const float CP = 0.92387953251128675613f, SP = 0.38268343236508977173f;
  float sn, cs;
  __sincosf(6.2831853071795864769f / 8192.0f * (float)tid, &sn, &cs);
  v2f w1{cs, sn};
  __syncthreads();
#pragma unroll
  for (int jj = 0; jj < 2; ++jj) {
    int j = jj * 512 + tid;
    v2f* p = a + (j + (j >> 4));
    v2f x[8];
#pragma unroll
    for (int q = 0; q < 8; ++q) x[q] = p[q * 1088];
    v2f tw[7];
    tw[0] = w1;
    twfill(tw);
#pragma unroll
    for (int q = 1; q < 8; ++q) x[q] = cmulf(x[q], tw[q - 1]);
    dft8<1>(x);  // x[4..7] unused below -> their final adds are DCE'd
#pragma unroll
    for (int q = 0; q < 4; ++q) out32[j + q * 1024] = packbf2(x[q].x, x[q].y);
    w1 = cmulf(w1, v2f{CP, SP});  // advance pos by 512
  }
}

// Phi2[k][f] = fwd-FFT( pad( (2/8192)*phi[2r,k], r<4096 ) ), scrambled order (matches k_conv)
__global__ __launch_bounds__(512) void k_phi(const float* __restrict__ phi,
                                             v2f* __restrict__ Phi2) {
  extern __shared__ v2f buf[];
  int k = blockIdx.x, tid = threadIdx.x;
  const float scale = 2.0f / 8192.0f;
  for (int r = tid; r < 4096; r += 512) {
    buf[r + (r >> 4)] = v2f{phi[(2 * r) * K_F + k] * scale, 0.0f};
    int r2i = r + 4096;
    buf[r2i + (r2i >> 4)] = v2f{0.0f, 0.0f};
  }
  pass_r8<10, -1, 512>(buf, tid);
  pass_r8<7, -1, 512>(buf, tid);
  pass_r8<4, -1, 512>(buf, tid);
  pass_r8<1, -1, 512>(buf, tid);
  __syncthreads();
  for (int j = tid; j < 4096; j += 512) {  // forward radix-2 (h=1)
    v2f* p = buf + (2 * j + ((2 * j) >> 4));
    v2f u = p[0], v = p[1];
    p[0] = u + v;
    p[1] = u - v;
  }
  __syncthreads();
  for (int f = tid; f < NFFT2; f += 512) Phi2[k * NFFT2 + f] = buf[f + (f >> 4)];
}

// W2[d][f] = sum_k Mf[k][d] * Phi2[k][f]  (packed bf16 re|im)
__global__ __launch_bounds__(256) void k_w2(const v2f* __restrict__ Phi2,
                                            const float* __restrict__ Mf,
                                            uint32_t* __restrict__ W2) {
  __shared__ v2f p[K_F][256];
  __shared__ float mf[K_F][32];
  int tid = threadIdx.x;
  int fc = blockIdx.x & 31, dc = blockIdx.x >> 5;
  int f0 = fc * 256, d0 = dc * 32;
  for (int i = tid; i < K_F * 256; i += 256) {
    int k = i >> 8, fl = i & 255;
    p[k][fl] = Phi2[k * NFFT2 + f0 + fl];
  }
  for (int i = tid; i < K_F * 32; i += 256) {
    int k = i >> 5, dl = i & 31;
    mf[k][dl] = Mf[k * D_CH + d0 + dl];
  }
  __syncthreads();
  for (int dl = 0; dl < 32; ++dl) {
    v2f acc = v2f{0.f, 0.f};
#pragma unroll
    for (int k = 0; k < K_F; ++k) acc += mf[k][dl] * p[k][tid];
    W2[(size_t)(d0 + dl) * NFFT2 + f0 + tid] = packbf2(acc.x, acc.y);
  }
}

// ---------- bf16 MFMA GEMM: m97 single-buffer structure, ALL-DMA staging ----------
__device__ __forceinline__ void gload_lds16(const void* g, void* l) {
  __builtin_amdgcn_global_load_lds(
      (const __attribute__((address_space(1))) void*)g,
      (__attribute__((address_space(3))) void*)l, 16, 0, 0);
}

__global__ __launch_bounds__(256) void k_gemm(const float* __restrict__ X,
                                              const uint16_t* __restrict__ MiT,
                                              uint16_t* __restrict__ Cp) {
  extern __shared__ char lds[];
  char* const As0 = lds;            // [128 rows][64 k] fp32, 16B-slot XOR swizzle (32 KB)
  char* const Bs0 = lds + 32768;    // [128 rows][64 k] bf16, XOR swizzle (16 KB)
  int tid = threadIdx.x;
  int lane = tid & 63, wid = tid >> 6;
  // bijective XCD swizzle: 1536 wg = 8 XCD x 192; 6 bn-siblings of a bm share one XCD L2
  int pb = blockIdx.x;
  int v = (pb & 7) * 192 + (pb >> 3);
  int bm = v / 6, bn = v % 6;
  int m0 = bm * 128, n0 = bn * 128;
  int wr = wid >> 1, wc = wid & 1;  // 2 x 2 waves, per-wave 64x64 output
  int lm = lane & 15, lg = lane >> 4;
  f32x4 acc[4][4] = {};

#define STAGE_A(k0)                                                     \
  _Pragma("unroll") for (int it = 0; it < 8; ++it) {                    \
    int s = it * 256 + tid;                                             \
    int row = s >> 4, s16 = s & 15;                                     \
    gload_lds16(X + (size_t)(m0 + row) * 768 + (k0) + ((s16 ^ (row & 7)) << 2), \
                As0 + (it * 256 + wid * 64) * 16);                      \
  }
#define STAGE_B(k0)                                                     \
  _Pragma("unroll") for (int it = 0; it < 4; ++it) {                    \
    int s = it * 256 + tid;                                             \
    int row = s >> 3;                                                   \
    int cb = ((s & 7) << 4) ^ ((row & 7) << 4);                         \
    gload_lds16(MiT + (size_t)(n0 + row) * 768 + (k0) + (cb >> 1),      \
                Bs0 + (it * 256 + wid * 64) * 16);                      \
  }

  for (int kt = 0; kt < 12; ++kt) {
    __syncthreads();  // previous tile's reads complete before overwrite
    STAGE_A(kt * 64);
    STAGE_B(kt * 64);
    asm volatile("s_waitcnt vmcnt(0)" ::: "memory");
    __syncthreads();
#pragma unroll
    for (int ks = 0; ks < 2; ++ks) {
      bf16x8 a[4], b[4];
#pragma unroll
      for (int mi = 0; mi < 4; ++mi) {
        int row = wr * 64 + mi * 16 + lm;
        const char* rb = As0 + row * 256;
        int s0 = ks * 8 + lg * 2;
        float4 flo = *(const float4*)(rb + ((s0 ^ (row & 7)) << 4));
        float4 fhi = *(const float4*)(rb + (((s0 + 1) ^ (row & 7)) << 4));
        uint4 u;
        u.x = pkbf(flo.x, flo.y);
        u.y = pkbf(flo.z, flo.w);
        u.z = pkbf(fhi.x, fhi.y);
        u.w = pkbf(fhi.z, fhi.w);
        a[mi] = *(const bf16x8*)&u;
      }
      int kbyte = (ks * 32 + lg * 8) * 2;
#pragma unroll
      for (int ni = 0; ni < 4; ++ni) {
        int row = wc * 64 + ni * 16 + lm;
        b[ni] = *(const bf16x8*)(Bs0 + row * 128 + (kbyte ^ ((row & 7) << 4)));
      }
#pragma unroll
      for (int mi = 0; mi < 4; ++mi)
#pragma unroll
        for (int ni = 0; ni < 4; ++ni)
          acc[mi][ni] = __builtin_amdgcn_mfma_f32_16x16x32_bf16(a[mi], b[ni], acc[mi][ni], 0, 0, 0);
    }
  }
#undef STAGE_A
#undef STAGE_B

  // epilogue: write transposed (B,D,L) bf16, 4 t-contig per lane
#pragma unroll
  for (int mi = 0; mi < 4; ++mi) {
#pragma unroll
    for (int ni = 0; ni < 4; ++ni) {
      int mg = m0 + wr * 64 + mi * 16 + lg * 4;
      int dd = n0 + wc * 64 + ni * 16 + lm;
      int bb = mg >> 13, t = mg & 8191;
      f32x4 vv = acc[mi][ni];
      uint2 o;
      o.x = packbf2(vv[0], vv[1]);
      o.y = packbf2(vv[2], vv[3]);
      *(uint2*)(Cp + ((size_t)bb * 768 + dd) * 8192 + t) = o;
    }
  }
}

// ---------- per-(b,d) FFT conv: 7-pass pipeline with in-register fused middle ----------
__global__ __launch_bounds__(512, 4) void k_conv(const uint16_t* __restrict__ xprojT,
                                                 const uint32_t* __restrict__ W2,
                                                 uint16_t* __restrict__ convo) {
  extern __shared__ v2f buf[];
  int tid = threadIdx.x;
  int bd = blockIdx.x;  // b*768 + d
  int d = bd % 768;
  const uint32_t* row32 = (const uint32_t*)(xprojT + (size_t)bd * 8192);
  p1_fused(buf, row32, tid);
  pass_r8<7, -1, 512>(buf, tid);
  pass_r8<4, -1, 512>(buf, tid);
  mid16(buf, W2 + (size_t)d * NFFT2, tid);
  pass_r8<4, 1, 512>(buf, tid);
  pass_r8<7, 1, 512>(buf, tid);
  last_fused(buf, (uint32_t*)(convo + (size_t)bd * 8192), tid);
}

// ---------- transpose (B,D,L) bf16 -> (B,L,D) fp32 ----------
__global__ __launch_bounds__(256) void k_tr(const uint16_t* __restrict__ convo,
                                            float* __restrict__ out) {
  __shared__ uint16_t tile[64][72];
  int tid = threadIdx.x;
  int bx = blockIdx.x;
  int b = bx / 1536;
  int r = bx - b * 1536;
  int d0 = (r >> 7) << 6;
  int t0 = (r & 127) << 6;
  {
    int rr = tid >> 3;
    int c8 = (tid & 7) << 3;
#pragma unroll
    for (int p = 0; p < 2; ++p) {
      int row = p * 32 + rr;
      uint4 v = *(const uint4*)(convo + ((size_t)(b * 768 + d0 + row)) * 8192 + t0 + c8);
      *(uint4*)&tile[row][c8] = v;
    }
  }
  __syncthreads();
  {
    int c4 = (tid & 15) << 2;
    int tg = tid >> 4;
#pragma unroll
    for (int p = 0; p < 4; ++p) {
      int tt = p * 16 + tg;
      float4 o;
      o.x = __uint_as_float((uint32_t)tile[c4 + 0][tt] << 16);
      o.y = __uint_as_float((uint32_t)tile[c4 + 1][tt] << 16);
      o.z = __uint_as_float((uint32_t)tile[c4 + 2][tt] << 16);
      o.w = __uint_as_float((uint32_t)tile[c4 + 3][tt] << 16);
      *(float4*)(out + ((size_t)b * 8192 + t0 + tt) * 768 + d0 + c4) = o;
    }
  }
}

extern "C" void kernel_launch(void* const* d_in, const int* in_sizes, int n_in,
                              void* d_out, int out_size, void* d_ws, size_t ws_size,
                              hipStream_t stream) {
  const float* x   = (const float*)d_in[0];
  const float* phi = (const float*)d_in[1];
  const float* Mi  = (const float*)d_in[2];
  const float* Mf  = (const float*)d_in[3];
  float* out = (float*)d_out;

  // d_out doubles as staging: [48MB,96MB) x_projT bf16 (B,D,L); [0,48MB) unused until k_tr
  uint16_t* xprojT = (uint16_t*)d_out + 25165824;

  char* ws = (char*)d_ws;
  uint16_t* convo = (uint16_t*)ws;               // 50,331,648 B  (B,D,L) bf16 conv result
  uint32_t* W2    = (uint32_t*)(ws + 50331648);  // 25,165,824 B  [768][8192] bf16 re|im
  v2f*      Phi2  = (v2f*)(ws + 75497472);       //  1,572,864 B  [24][8192] fp32 complex
  uint16_t* MiT   = (uint16_t*)(ws + 77070336);  //  1,179,648 B  [768][768] bf16

  k_mit<<<2304, 256, 0, stream>>>(Mi, MiT);
  k_phi<<<24, 512, LDS_BYTES, stream>>>(phi, Phi2);
  k_w2<<<768, 256, 0, stream>>>(Phi2, Mf, W2);
  k_gemm<<<1536, 256, GEMM_LDS, stream>>>(x, MiT, xprojT);
  k_conv<<<3072, 512, LDS_BYTES, stream>>>(xprojT, W2, convo);
  k_tr<<<6144, 256, 0, stream>>>(convo, out);
}